// Round 1
// 764.390 us; speedup vs baseline: 1.1959x; 1.1959x over previous
//
#include <hip/hip_runtime.h>
#include <hip/hip_bf16.h>
#include <stdint.h>

#define NN 100000   // nodes
#define NE 500000   // edges per head
#define NA 4        // angle heads
#define DIM 128     // bond/hidden dim
#define LDA 136     // padded LDS row stride (bf16 elems)

#define NBINS (NA * NN)          // 400000 (k-major bins)
#define SCAN_CHUNK 1024          // elems per scan block (256 thr x 4)
#define NBLK ((NBINS + SCAN_CHUNK - 1) / SCAN_CHUNK)  // 391

typedef __attribute__((ext_vector_type(8))) short bf16x8;
typedef __attribute__((ext_vector_type(4))) float f32x4;
typedef unsigned short u16;
typedef unsigned int u32;
typedef unsigned long long u64;

__device__ __forceinline__ u16 f2bf(float x) {
    u32 u = __float_as_uint(x);
    u32 r = (u + 0x7fffu + ((u >> 16) & 1u)) >> 16;  // RNE
    return (u16)r;
}
__device__ __forceinline__ float bf2f(u16 h) {
    return __uint_as_float(((u32)h) << 16);
}
__device__ __forceinline__ float fast_tanh(float x) {
    float t = __expf(2.0f * x);
    return 1.0f - __fdividef(2.0f, t + 1.0f);
}

// ---- cast bond_feat fp32 -> bf16 (8 elems/thread) ----
__global__ __launch_bounds__(256) void cast_bond(const float* __restrict__ x,
                                                 u16* __restrict__ y) {
    int i = blockIdx.x * 256 + threadIdx.x;
    if (i >= NN * DIM / 8) return;
    const float4* xv = (const float4*)x;
    float4 a = xv[2 * i], b = xv[2 * i + 1];
    uint4 o;
    o.x = (u32)f2bf(a.x) | ((u32)f2bf(a.y) << 16);
    o.y = (u32)f2bf(a.z) | ((u32)f2bf(a.w) << 16);
    o.z = (u32)f2bf(b.x) | ((u32)f2bf(b.y) << 16);
    o.w = (u32)f2bf(b.z) | ((u32)f2bf(b.w) << 16);
    ((uint4*)y)[i] = o;
}

// ---- pack W [4][256][128] fp32 -> WbT [8 slabs][128 out][128 in] bf16 ----
__global__ __launch_bounds__(256) void pack_w(const float* __restrict__ W,
                                              u16* __restrict__ WbT) {
    int i = blockIdx.x * 256 + threadIdx.x;  // 131072 total
    int d = i & 127;
    int o = (i >> 7) & 127;
    int st = i >> 14;  // slab
    WbT[i] = f2bf(W[(size_t)(st * 128 + d) * 128 + o]);
}

// ---- Y[slab][node][128] bf16 = bond @ Wslab (+bias on t==0 slabs) ----
__global__ __launch_bounds__(256) void gemm_y(const u16* __restrict__ bondB,
                                              const u16* __restrict__ WbT,
                                              const float* __restrict__ bias,
                                              u16* __restrict__ Y) {
    __shared__ __align__(16) u16 As[64 * LDA];
    __shared__ __align__(16) u16 Bs[128 * LDA];
    const int slab = blockIdx.y;
    const int node0 = blockIdx.x * 64;
    const int tid = threadIdx.x;

#pragma unroll
    for (int it = 0; it < 4; ++it) {
        int idx = it * 256 + tid;
        int row = idx >> 4, ch = idx & 15;
        int gr = node0 + row;
        if (gr >= NN) gr = NN - 1;
        *(uint4*)&As[row * LDA + ch * 8] = *(const uint4*)&bondB[(size_t)gr * DIM + ch * 8];
    }
    const u16* Wslab = WbT + (size_t)slab * DIM * DIM;
#pragma unroll
    for (int it = 0; it < 8; ++it) {
        int idx = it * 256 + tid;
        int row = idx >> 4, ch = idx & 15;
        *(uint4*)&Bs[row * LDA + ch * 8] = *(const uint4*)&Wslab[idx * 8];
    }
    __syncthreads();

    const int wave = tid >> 6, lane = tid & 63;
    const int m0 = wave * 16;
    const int lrow = lane & 15;
    const int lk8 = (lane >> 4) * 8;

    f32x4 acc[8] = {};
#pragma unroll
    for (int kk = 0; kk < 4; ++kk) {
        int ko = kk * 32 + lk8;
        bf16x8 a = *(const bf16x8*)&As[(m0 + lrow) * LDA + ko];
#pragma unroll
        for (int nb = 0; nb < 8; ++nb) {
            bf16x8 b = *(const bf16x8*)&Bs[(nb * 16 + lrow) * LDA + ko];
            acc[nb] = __builtin_amdgcn_mfma_f32_16x16x32_bf16(a, b, acc[nb], 0, 0, 0);
        }
    }

    const int k = slab >> 1, t = slab & 1;
    const int rbase = (lane >> 4) * 4;
#pragma unroll
    for (int nb = 0; nb < 8; ++nb) {
        int o = nb * 16 + lrow;
        float bv = (t == 0) ? bias[k * DIM + o] : 0.0f;
#pragma unroll
        for (int r = 0; r < 4; ++r) {
            int node = node0 + m0 + rbase + r;
            if (node < NN)
                Y[(size_t)slab * NN * DIM + (size_t)node * DIM + o] = f2bf(acc[nb][r] + bv);
        }
    }
}

// ==================== CSR build (counting sort by dst) ====================

__global__ __launch_bounds__(256) void hist_kernel(const int* __restrict__ ei,
                                                   int* __restrict__ counts) {
    int k = blockIdx.y;
    int e = blockIdx.x * 256 + threadIdx.x;
    if (e >= NE) return;
    int dst = ei[(size_t)(k * 2 + 1) * NE + e];
    atomicAdd(&counts[k * NN + dst], 1);
}

__global__ __launch_bounds__(256) void scan_reduce(const int* __restrict__ counts,
                                                   int* __restrict__ blockSums) {
    int b = blockIdx.x, t = threadIdx.x;
    int base = b * SCAN_CHUNK + t * 4;
    int s = 0;
#pragma unroll
    for (int u = 0; u < 4; ++u) {
        int i = base + u;
        if (i < NBINS) s += counts[i];
    }
    __shared__ int red[256];
    red[t] = s;
    __syncthreads();
    for (int off = 128; off > 0; off >>= 1) {
        if (t < off) red[t] += red[t + off];
        __syncthreads();
    }
    if (t == 0) blockSums[b] = red[0];
}

__global__ void scan_bases(int* __restrict__ blockSums, int* __restrict__ offsets) {
    __shared__ int lds[512];
    int t = threadIdx.x;
    lds[t] = (t < NBLK) ? blockSums[t] : 0;
    __syncthreads();
    if (t == 0) {
        int run = 0;
        for (int i = 0; i < NBLK; ++i) {
            int v = lds[i];
            lds[i] = run;
            run += v;
        }
        offsets[NBINS] = run;  // total = NA*NE
    }
    __syncthreads();
    if (t < NBLK) blockSums[t] = lds[t];
}

__global__ __launch_bounds__(256) void scan_write(const int* __restrict__ counts,
                                                  const int* __restrict__ blockBases,
                                                  int* __restrict__ offsets,
                                                  int* __restrict__ woff) {
    int b = blockIdx.x, t = threadIdx.x;
    int base = b * SCAN_CHUNK + t * 4;
    int v[4];
    int s = 0;
#pragma unroll
    for (int u = 0; u < 4; ++u) {
        int i = base + u;
        v[u] = (i < NBINS) ? counts[i] : 0;
        s += v[u];
    }
    __shared__ int lds[256];
    lds[t] = s;
    __syncthreads();
    for (int off = 1; off < 256; off <<= 1) {
        int add = (t >= off) ? lds[t - off] : 0;
        __syncthreads();
        lds[t] += add;
        __syncthreads();
    }
    int run = blockBases[b] + lds[t] - s;  // exclusive within block + block base
#pragma unroll
    for (int u = 0; u < 4; ++u) {
        int i = base + u;
        if (i < NBINS) {
            offsets[i] = run;
            woff[i] = run;
            run += v[u];
        }
    }
}

__global__ __launch_bounds__(256) void scatter_kernel(const int* __restrict__ ei,
                                                      int* __restrict__ woff,
                                                      int* __restrict__ sorted_src) {
    int k = blockIdx.y;
    int e = blockIdx.x * 256 + threadIdx.x;
    if (e >= NE) return;
    int src = ei[(size_t)(k * 2 + 0) * NE + e];
    int dst = ei[(size_t)(k * 2 + 1) * NE + e];
    int pos = atomicAdd(&woff[k * NN + dst], 1);
    sorted_src[pos] = src;
}

// ---- gather edge phase: one wave per (node, head), no atomics ----
// v2: batched src fetch (1 coalesced load / 64 edges) + v_readlane broadcast
//     (src in SGPR -> SALU addressing), 4-deep edge unroll (MLP 2 -> 8),
//     nontemporal out store (don't evict hot Y2/bondB set from L3).
__global__ __launch_bounds__(256) void gather_kernel(const int* __restrict__ offsets,
                                                     const int* __restrict__ sorted_src,
                                                     const u16* __restrict__ Y,
                                                     const u16* __restrict__ bondB,
                                                     float* __restrict__ out) {
    const int k = blockIdx.y;
    const int node = blockIdx.x * 4 + (threadIdx.x >> 6);
    const int lane = threadIdx.x & 63;
    const int f = lane * 2;
    const int bin = k * NN + node;

    // wave-uniform bounds -> force into SGPRs so loop control is scalar
    int base = __builtin_amdgcn_readfirstlane(offsets[bin]);
    int cnt = __builtin_amdgcn_readfirstlane(offsets[bin + 1]) - base;

    const u16* __restrict__ Y1p = Y + (size_t)(2 * k) * NN * DIM;
    const u16* __restrict__ Y2p = Y + (size_t)(2 * k + 1) * NN * DIM;

    const u32 y1 = *(const u32*)&Y1p[(u32)node * DIM + f];
    const float y1a = __uint_as_float(y1 << 16);
    const float y1b = __uint_as_float(y1 & 0xffff0000u);
    float acc0 = 0.0f, acc1 = 0.0f;

#define EDGE(w, x)                                                      \
    {                                                                   \
        float p0 = y1a + __uint_as_float((w) << 16);                    \
        float p1 = y1b + __uint_as_float((w) & 0xffff0000u);            \
        float t0 = fast_tanh(p0);                                       \
        float t1 = fast_tanh(p1);                                       \
        acc0 = fmaf(t0, __uint_as_float((x) << 16), acc0);              \
        acc1 = fmaf(t1, __uint_as_float((x) & 0xffff0000u), acc1);      \
    }

    while (cnt > 0) {
        const int take = (cnt < 64) ? cnt : 64;
        // one coalesced load grabs up to 64 src indices for this bin chunk
        const int srcl = sorted_src[base + ((lane < take) ? lane : (take - 1))];
        int e = 0;
        for (; e + 4 <= take; e += 4) {
            const int s0 = __builtin_amdgcn_readlane(srcl, e);
            const int s1 = __builtin_amdgcn_readlane(srcl, e + 1);
            const int s2 = __builtin_amdgcn_readlane(srcl, e + 2);
            const int s3 = __builtin_amdgcn_readlane(srcl, e + 3);
            const u32 w0 = *(const u32*)&Y2p[(u32)s0 * DIM + f];
            const u32 x0 = *(const u32*)&bondB[(u32)s0 * DIM + f];
            const u32 w1 = *(const u32*)&Y2p[(u32)s1 * DIM + f];
            const u32 x1 = *(const u32*)&bondB[(u32)s1 * DIM + f];
            const u32 w2 = *(const u32*)&Y2p[(u32)s2 * DIM + f];
            const u32 x2 = *(const u32*)&bondB[(u32)s2 * DIM + f];
            const u32 w3 = *(const u32*)&Y2p[(u32)s3 * DIM + f];
            const u32 x3 = *(const u32*)&bondB[(u32)s3 * DIM + f];
            EDGE(w0, x0);
            EDGE(w1, x1);
            EDGE(w2, x2);
            EDGE(w3, x3);
        }
        for (; e < take; ++e) {
            const int s = __builtin_amdgcn_readlane(srcl, e);
            const u32 w = *(const u32*)&Y2p[(u32)s * DIM + f];
            const u32 x = *(const u32*)&bondB[(u32)s * DIM + f];
            EDGE(w, x);
        }
        base += take;
        cnt -= take;
    }
#undef EDGE

    // streaming (nontemporal) 8B store: out is written once, never re-read
    u64 uv = ((u64)__float_as_uint(acc1) << 32) | (u64)__float_as_uint(acc0);
    __builtin_nontemporal_store(uv, (u64*)(out + (size_t)node * (NA * DIM) + k * DIM + f));
}

// ---- legacy atomic edge kernel (mid fallback) ----
__global__ __launch_bounds__(256) void edge_kernel(const int* __restrict__ ei,
                                                   const u16* __restrict__ Y,
                                                   const float* __restrict__ bond,
                                                   float* __restrict__ out) {
    const int k = blockIdx.y;
    const int e = blockIdx.x * 4 + (threadIdx.x >> 6);
    const int lane = threadIdx.x & 63;
    const int src = ei[(size_t)(k * 2 + 0) * NE + e];
    const int dst = ei[(size_t)(k * 2 + 1) * NE + e];
    const int f = lane * 2;
    const u32 y1p = *(const u32*)&Y[((size_t)(k * 2 + 0) * NN + dst) * DIM + f];
    const u32 y2p = *(const u32*)&Y[((size_t)(k * 2 + 1) * NN + src) * DIM + f];
    const float2 xj = *(const float2*)&bond[(size_t)src * DIM + f];
    float p0 = bf2f((u16)(y1p & 0xffffu)) + bf2f((u16)(y2p & 0xffffu));
    float p1 = bf2f((u16)(y1p >> 16)) + bf2f((u16)(y2p >> 16));
    float a0 = fast_tanh(p0);
    float a1 = fast_tanh(p1);
    float* op = out + (size_t)dst * (NA * DIM) + k * DIM + f;
    atomicAdd(op, a0 * xj.x);
    atomicAdd(op + 1, a1 * xj.y);
}

// ---- ultra fallback: direct per-edge compute ----
__global__ __launch_bounds__(128) void fallback_edge(const float* __restrict__ bond,
                                                     const int* __restrict__ ei,
                                                     const float* __restrict__ W,
                                                     const float* __restrict__ bias,
                                                     float* __restrict__ out) {
    __shared__ float xi[DIM], xj[DIM];
    const int k = blockIdx.y;
    const int e = blockIdx.x;
    const int o = threadIdx.x;
    const int src = ei[(size_t)(k * 2 + 0) * NE + e];
    const int dst = ei[(size_t)(k * 2 + 1) * NE + e];
    xi[o] = bond[(size_t)dst * DIM + o];
    xj[o] = bond[(size_t)src * DIM + o];
    __syncthreads();
    const float* Wk = W + (size_t)k * 2 * DIM * DIM;
    float acc = bias[k * DIM + o];
    for (int din = 0; din < DIM; ++din) {
        acc += xi[din] * Wk[din * DIM + o];
        acc += xj[din] * Wk[(DIM + din) * DIM + o];
    }
    float alpha = fast_tanh(acc);
    atomicAdd(&out[(size_t)dst * (NA * DIM) + k * DIM + o], alpha * xj[o]);
}

static inline size_t align256(size_t x) { return (x + 255) & ~(size_t)255; }

extern "C" void kernel_launch(void* const* d_in, const int* in_sizes, int n_in,
                              void* d_out, int out_size, void* d_ws, size_t ws_size,
                              hipStream_t stream) {
    const float* bond = (const float*)d_in[0];
    const int* ei = (const int*)d_in[1];
    const float* W = (const float*)d_in[2];
    const float* bias = (const float*)d_in[3];
    float* out = (float*)d_out;

    const size_t wbt_bytes = align256((size_t)NA * 2 * DIM * DIM * 2);   // 256 KB
    const size_t bondb_bytes = align256((size_t)NN * DIM * 2);           // 25.6 MB
    const size_t y_bytes = align256((size_t)NA * 2 * NN * DIM * 2);      // 204.8 MB
    const size_t counts_bytes = align256((size_t)NBINS * 4);             // 1.6 MB
    const size_t offsets_bytes = align256(((size_t)NBINS + 1) * 4);      // 1.6 MB
    const size_t woff_bytes = align256((size_t)NBINS * 4);               // 1.6 MB
    const size_t bsum_bytes = align256((size_t)512 * 4);                 // 2 KB
    const size_t ssrc_bytes = align256((size_t)NA * NE * 4);             // 8 MB

    const size_t base_bytes = wbt_bytes + bondb_bytes + y_bytes;
    const size_t full_bytes = base_bytes + counts_bytes + offsets_bytes +
                              woff_bytes + bsum_bytes + ssrc_bytes;

    if (ws_size >= full_bytes) {
        char* p = (char*)d_ws;
        u16* WbT = (u16*)p;                 p += wbt_bytes;
        u16* bondB = (u16*)p;               p += bondb_bytes;
        u16* Y = (u16*)p;                   p += y_bytes;
        int* counts = (int*)p;              p += counts_bytes;
        int* offsets = (int*)p;             p += offsets_bytes;
        int* woff = (int*)p;                p += woff_bytes;
        int* bsum = (int*)p;                p += bsum_bytes;
        int* ssrc = (int*)p;

        // projections
        pack_w<<<dim3(131072 / 256), 256, 0, stream>>>(W, WbT);
        cast_bond<<<dim3((NN * DIM / 8 + 255) / 256), 256, 0, stream>>>(bond, bondB);
        gemm_y<<<dim3((NN + 63) / 64, NA * 2), 256, 0, stream>>>(bondB, WbT, bias, Y);

        // CSR build (overlaps gemm in-order on stream, all cheap)
        hipMemsetAsync(counts, 0, (size_t)NBINS * 4, stream);
        hist_kernel<<<dim3((NE + 255) / 256, NA), 256, 0, stream>>>(ei, counts);
        scan_reduce<<<dim3(NBLK), 256, 0, stream>>>(counts, bsum);
        scan_bases<<<dim3(1), 512, 0, stream>>>(bsum, offsets);
        scan_write<<<dim3(NBLK), 256, 0, stream>>>(counts, bsum, offsets, woff);
        scatter_kernel<<<dim3((NE + 255) / 256, NA), 256, 0, stream>>>(ei, woff, ssrc);

        // gather phase: one wave per (node, head); writes every output once
        gather_kernel<<<dim3(NN / 4, NA), 256, 0, stream>>>(offsets, ssrc, Y, bondB, out);
    } else if (ws_size >= base_bytes) {
        u16* WbT = (u16*)d_ws;
        u16* bondB = (u16*)((char*)d_ws + wbt_bytes);
        u16* Y = (u16*)((char*)d_ws + wbt_bytes + bondb_bytes);
        hipMemsetAsync(d_out, 0, (size_t)out_size * sizeof(float), stream);
        pack_w<<<dim3(131072 / 256), 256, 0, stream>>>(W, WbT);
        cast_bond<<<dim3((NN * DIM / 8 + 255) / 256), 256, 0, stream>>>(bond, bondB);
        gemm_y<<<dim3((NN + 63) / 64, NA * 2), 256, 0, stream>>>(bondB, WbT, bias, Y);
        edge_kernel<<<dim3(NE / 4, NA), 256, 0, stream>>>(ei, Y, bond, out);
    } else {
        hipMemsetAsync(d_out, 0, (size_t)out_size * sizeof(float), stream);
        fallback_edge<<<dim3(NE, NA), 128, 0, stream>>>(bond, ei, W, bias, out);
    }
}

// Round 3
// 763.505 us; speedup vs baseline: 1.1973x; 1.0012x over previous
//
#include <hip/hip_runtime.h>
#include <hip/hip_bf16.h>
#include <stdint.h>

#define NN 100000   // nodes
#define NE 500000   // edges per head
#define NA 4        // angle heads
#define DIM 128     // bond/hidden dim
#define LDA 136     // padded LDS row stride (bf16 elems)

#define NBINS (NA * NN)          // 400000 (k-major bins)
#define SCAN_CHUNK 1024          // elems per scan block (256 thr x 4)
#define NBLK ((NBINS + SCAN_CHUNK - 1) / SCAN_CHUNK)  // 391

typedef __attribute__((ext_vector_type(8))) short bf16x8;
typedef __attribute__((ext_vector_type(4))) float f32x4;
typedef unsigned short u16;
typedef unsigned int u32;
typedef unsigned long long u64;

__device__ __forceinline__ u16 f2bf(float x) {
    u32 u = __float_as_uint(x);
    u32 r = (u + 0x7fffu + ((u >> 16) & 1u)) >> 16;  // RNE
    return (u16)r;
}
__device__ __forceinline__ float bf2f(u16 h) {
    return __uint_as_float(((u32)h) << 16);
}
__device__ __forceinline__ float fast_tanh(float x) {
    float t = __expf(2.0f * x);
    return 1.0f - __fdividef(2.0f, t + 1.0f);
}

// ---- cast bond_feat fp32 -> bf16 (8 elems/thread) ----
__global__ __launch_bounds__(256) void cast_bond(const float* __restrict__ x,
                                                 u16* __restrict__ y) {
    int i = blockIdx.x * 256 + threadIdx.x;
    if (i >= NN * DIM / 8) return;
    const float4* xv = (const float4*)x;
    float4 a = xv[2 * i], b = xv[2 * i + 1];
    uint4 o;
    o.x = (u32)f2bf(a.x) | ((u32)f2bf(a.y) << 16);
    o.y = (u32)f2bf(a.z) | ((u32)f2bf(a.w) << 16);
    o.z = (u32)f2bf(b.x) | ((u32)f2bf(b.y) << 16);
    o.w = (u32)f2bf(b.z) | ((u32)f2bf(b.w) << 16);
    ((uint4*)y)[i] = o;
}

// ---- pack W [4][256][128] fp32 -> WbT [8 slabs][128 out][128 in] bf16 ----
__global__ __launch_bounds__(256) void pack_w(const float* __restrict__ W,
                                              u16* __restrict__ WbT) {
    int i = blockIdx.x * 256 + threadIdx.x;  // 131072 total
    int d = i & 127;
    int o = (i >> 7) & 127;
    int st = i >> 14;  // slab
    WbT[i] = f2bf(W[(size_t)(st * 128 + d) * 128 + o]);
}

// ---- Y[slab][node][128] bf16 = bond @ Wslab (+bias on t==0 slabs) ----
// v3: 8-slab loop per block (As staged once, 8x fewer blocks); MFMA
//     orientation and epilogue are verbatim the hardware-proven v1 forms.
__global__ __launch_bounds__(256) void gemm_y(const u16* __restrict__ bondB,
                                              const u16* __restrict__ WbT,
                                              const float* __restrict__ bias,
                                              u16* __restrict__ Y) {
    __shared__ __align__(16) u16 As[64 * LDA];
    __shared__ __align__(16) u16 Bs[128 * LDA];
    const int node0 = blockIdx.x * 64;
    const int tid = threadIdx.x;

#pragma unroll
    for (int it = 0; it < 4; ++it) {
        int idx = it * 256 + tid;
        int row = idx >> 4, ch = idx & 15;
        int gr = node0 + row;
        if (gr >= NN) gr = NN - 1;
        *(uint4*)&As[row * LDA + ch * 8] = *(const uint4*)&bondB[(size_t)gr * DIM + ch * 8];
    }

    const int wave = tid >> 6, lane = tid & 63;
    const int m0 = wave * 16;
    const int lrow = lane & 15;
    const int lk8 = (lane >> 4) * 8;
    const int rbase = (lane >> 4) * 4;

    for (int slab = 0; slab < 8; ++slab) {
        __syncthreads();  // all waves done reading Bs (or done staging As)
        const u16* Wslab = WbT + (size_t)slab * DIM * DIM;
#pragma unroll
        for (int it = 0; it < 8; ++it) {
            int idx = it * 256 + tid;
            *(uint4*)&Bs[(idx >> 4) * LDA + (idx & 15) * 8] = *(const uint4*)&Wslab[idx * 8];
        }
        __syncthreads();

        f32x4 acc[8] = {};
#pragma unroll
        for (int kk = 0; kk < 4; ++kk) {
            int ko = kk * 32 + lk8;
            bf16x8 a = *(const bf16x8*)&As[(m0 + lrow) * LDA + ko];
#pragma unroll
            for (int nb = 0; nb < 8; ++nb) {
                bf16x8 b = *(const bf16x8*)&Bs[(nb * 16 + lrow) * LDA + ko];
                acc[nb] = __builtin_amdgcn_mfma_f32_16x16x32_bf16(a, b, acc[nb], 0, 0, 0);
            }
        }

        const int k = slab >> 1, t = slab & 1;
#pragma unroll
        for (int nb = 0; nb < 8; ++nb) {
            int o = nb * 16 + lrow;
            float bv = (t == 0) ? bias[k * DIM + o] : 0.0f;
#pragma unroll
            for (int r = 0; r < 4; ++r) {
                int node = node0 + m0 + rbase + r;
                if (node < NN)
                    Y[(size_t)slab * NN * DIM + (size_t)node * DIM + o] = f2bf(acc[nb][r] + bv);
            }
        }
    }
}

// ==================== CSR build (counting sort by dst) ====================

__global__ __launch_bounds__(256) void hist_kernel(const int* __restrict__ ei,
                                                   int* __restrict__ counts) {
    int k = blockIdx.y;
    int e = blockIdx.x * 256 + threadIdx.x;
    if (e >= NE) return;
    int dst = ei[(size_t)(k * 2 + 1) * NE + e];
    atomicAdd(&counts[k * NN + dst], 1);
}

__global__ __launch_bounds__(256) void scan_reduce(const int* __restrict__ counts,
                                                   int* __restrict__ blockSums) {
    int b = blockIdx.x, t = threadIdx.x;
    int base = b * SCAN_CHUNK + t * 4;
    int s = 0;
#pragma unroll
    for (int u = 0; u < 4; ++u) {
        int i = base + u;
        if (i < NBINS) s += counts[i];
    }
    __shared__ int red[256];
    red[t] = s;
    __syncthreads();
    for (int off = 128; off > 0; off >>= 1) {
        if (t < off) red[t] += red[t + off];
        __syncthreads();
    }
    if (t == 0) blockSums[b] = red[0];
}

__global__ void scan_bases(int* __restrict__ blockSums, int* __restrict__ offsets) {
    __shared__ int lds[512];
    int t = threadIdx.x;
    lds[t] = (t < NBLK) ? blockSums[t] : 0;
    __syncthreads();
    if (t == 0) {
        int run = 0;
        for (int i = 0; i < NBLK; ++i) {
            int v = lds[i];
            lds[i] = run;
            run += v;
        }
        offsets[NBINS] = run;  // total = NA*NE
    }
    __syncthreads();
    if (t < NBLK) blockSums[t] = lds[t];
}

__global__ __launch_bounds__(256) void scan_write(const int* __restrict__ counts,
                                                  const int* __restrict__ blockBases,
                                                  int* __restrict__ offsets,
                                                  int* __restrict__ woff) {
    int b = blockIdx.x, t = threadIdx.x;
    int base = b * SCAN_CHUNK + t * 4;
    int v[4];
    int s = 0;
#pragma unroll
    for (int u = 0; u < 4; ++u) {
        int i = base + u;
        v[u] = (i < NBINS) ? counts[i] : 0;
        s += v[u];
    }
    __shared__ int lds[256];
    lds[t] = s;
    __syncthreads();
    for (int off = 1; off < 256; off <<= 1) {
        int add = (t >= off) ? lds[t - off] : 0;
        __syncthreads();
        lds[t] += add;
        __syncthreads();
    }
    int run = blockBases[b] + lds[t] - s;  // exclusive within block + block base
#pragma unroll
    for (int u = 0; u < 4; ++u) {
        int i = base + u;
        if (i < NBINS) {
            offsets[i] = run;
            woff[i] = run;
            run += v[u];
        }
    }
}

__global__ __launch_bounds__(256) void scatter_kernel(const int* __restrict__ ei,
                                                      int* __restrict__ woff,
                                                      int* __restrict__ sorted_src) {
    int k = blockIdx.y;
    int e = blockIdx.x * 256 + threadIdx.x;
    if (e >= NE) return;
    int src = ei[(size_t)(k * 2 + 0) * NE + e];
    int dst = ei[(size_t)(k * 2 + 1) * NE + e];
    int pos = atomicAdd(&woff[k * NN + dst], 1);
    sorted_src[pos] = src;
}

// ---- gather edge phase: one wave per (node, head), no atomics ----
// v4: v2's proven loop/load structure (batched src + readlane + 4-deep
//     unroll + nt store); tanh chain uses scalar fused reciprocal:
//     one v_rcp serves both features (4 trans -> 3 trans per edge).
__global__ __launch_bounds__(256) void gather_kernel(const int* __restrict__ offsets,
                                                     const int* __restrict__ sorted_src,
                                                     const u16* __restrict__ Y,
                                                     const u16* __restrict__ bondB,
                                                     float* __restrict__ out) {
    const int k = blockIdx.y;
    const int node = blockIdx.x * 4 + (threadIdx.x >> 6);
    const int lane = threadIdx.x & 63;
    const int f = lane * 2;
    const int bin = k * NN + node;

    int base = __builtin_amdgcn_readfirstlane(offsets[bin]);
    int cnt = __builtin_amdgcn_readfirstlane(offsets[bin + 1]) - base;

    const u16* __restrict__ Y1p = Y + (size_t)(2 * k) * NN * DIM;
    const u16* __restrict__ Y2p = Y + (size_t)(2 * k + 1) * NN * DIM;

    const u32 y1 = *(const u32*)&Y1p[(u32)node * DIM + f];
    const float y1a = __uint_as_float(y1 << 16);
    const float y1b = __uint_as_float(y1 & 0xffff0000u);
    float acc0 = 0.0f, acc1 = 0.0f;

    // tanh(p) = 1 - 2/(exp(2p)+1); the two features share one reciprocal:
    // r = 1/(d0*d1); 1/d0 = r*d1, 1/d1 = r*d0.  (|p|<=~16 -> no overflow)
#define EDGE(w, x)                                                      \
    {                                                                   \
        float p0 = y1a + __uint_as_float((w) << 16);                    \
        float p1 = y1b + __uint_as_float((w) & 0xffff0000u);            \
        float e0 = __expf(2.0f * p0);                                   \
        float e1 = __expf(2.0f * p1);                                   \
        float d0 = e0 + 1.0f;                                           \
        float d1 = e1 + 1.0f;                                           \
        float r = __fdividef(1.0f, d0 * d1);                            \
        float th0 = fmaf(-2.0f * d1, r, 1.0f);                          \
        float th1 = fmaf(-2.0f * d0, r, 1.0f);                          \
        acc0 = fmaf(th0, __uint_as_float((x) << 16), acc0);             \
        acc1 = fmaf(th1, __uint_as_float((x) & 0xffff0000u), acc1);     \
    }

    while (cnt > 0) {
        const int take = (cnt < 64) ? cnt : 64;
        const int srcl = sorted_src[base + ((lane < take) ? lane : (take - 1))];
        int e = 0;
        for (; e + 4 <= take; e += 4) {
            const int s0 = __builtin_amdgcn_readlane(srcl, e);
            const int s1 = __builtin_amdgcn_readlane(srcl, e + 1);
            const int s2 = __builtin_amdgcn_readlane(srcl, e + 2);
            const int s3 = __builtin_amdgcn_readlane(srcl, e + 3);
            const u32 w0 = *(const u32*)&Y2p[(u32)s0 * DIM + f];
            const u32 x0 = *(const u32*)&bondB[(u32)s0 * DIM + f];
            const u32 w1 = *(const u32*)&Y2p[(u32)s1 * DIM + f];
            const u32 x1 = *(const u32*)&bondB[(u32)s1 * DIM + f];
            const u32 w2 = *(const u32*)&Y2p[(u32)s2 * DIM + f];
            const u32 x2 = *(const u32*)&bondB[(u32)s2 * DIM + f];
            const u32 w3 = *(const u32*)&Y2p[(u32)s3 * DIM + f];
            const u32 x3 = *(const u32*)&bondB[(u32)s3 * DIM + f];
            EDGE(w0, x0);
            EDGE(w1, x1);
            EDGE(w2, x2);
            EDGE(w3, x3);
        }
        for (; e < take; ++e) {
            const int s = __builtin_amdgcn_readlane(srcl, e);
            const u32 w = *(const u32*)&Y2p[(u32)s * DIM + f];
            const u32 x = *(const u32*)&bondB[(u32)s * DIM + f];
            EDGE(w, x);
        }
        base += take;
        cnt -= take;
    }
#undef EDGE

    u64 uv = ((u64)__float_as_uint(acc1) << 32) | (u64)__float_as_uint(acc0);
    __builtin_nontemporal_store(uv, (u64*)(out + (size_t)node * (NA * DIM) + k * DIM + f));
}

// ---- legacy atomic edge kernel (mid fallback) ----
__global__ __launch_bounds__(256) void edge_kernel(const int* __restrict__ ei,
                                                   const u16* __restrict__ Y,
                                                   const float* __restrict__ bond,
                                                   float* __restrict__ out) {
    const int k = blockIdx.y;
    const int e = blockIdx.x * 4 + (threadIdx.x >> 6);
    const int lane = threadIdx.x & 63;
    const int src = ei[(size_t)(k * 2 + 0) * NE + e];
    const int dst = ei[(size_t)(k * 2 + 1) * NE + e];
    const int f = lane * 2;
    const u32 y1p = *(const u32*)&Y[((size_t)(k * 2 + 0) * NN + dst) * DIM + f];
    const u32 y2p = *(const u32*)&Y[((size_t)(k * 2 + 1) * NN + src) * DIM + f];
    const float2 xj = *(const float2*)&bond[(size_t)src * DIM + f];
    float p0 = bf2f((u16)(y1p & 0xffffu)) + bf2f((u16)(y2p & 0xffffu));
    float p1 = bf2f((u16)(y1p >> 16)) + bf2f((u16)(y2p >> 16));
    float a0 = fast_tanh(p0);
    float a1 = fast_tanh(p1);
    float* op = out + (size_t)dst * (NA * DIM) + k * DIM + f;
    atomicAdd(op, a0 * xj.x);
    atomicAdd(op + 1, a1 * xj.y);
}

// ---- ultra fallback: direct per-edge compute ----
__global__ __launch_bounds__(128) void fallback_edge(const float* __restrict__ bond,
                                                     const int* __restrict__ ei,
                                                     const float* __restrict__ W,
                                                     const float* __restrict__ bias,
                                                     float* __restrict__ out) {
    __shared__ float xi[DIM], xj[DIM];
    const int k = blockIdx.y;
    const int e = blockIdx.x;
    const int o = threadIdx.x;
    const int src = ei[(size_t)(k * 2 + 0) * NE + e];
    const int dst = ei[(size_t)(k * 2 + 1) * NE + e];
    xi[o] = bond[(size_t)dst * DIM + o];
    xj[o] = bond[(size_t)src * DIM + o];
    __syncthreads();
    const float* Wk = W + (size_t)k * 2 * DIM * DIM;
    float acc = bias[k * DIM + o];
    for (int din = 0; din < DIM; ++din) {
        acc += xi[din] * Wk[din * DIM + o];
        acc += xj[din] * Wk[(DIM + din) * DIM + o];
    }
    float alpha = fast_tanh(acc);
    atomicAdd(&out[(size_t)dst * (NA * DIM) + k * DIM + o], alpha * xj[o]);
}

static inline size_t align256(size_t x) { return (x + 255) & ~(size_t)255; }

extern "C" void kernel_launch(void* const* d_in, const int* in_sizes, int n_in,
                              void* d_out, int out_size, void* d_ws, size_t ws_size,
                              hipStream_t stream) {
    const float* bond = (const float*)d_in[0];
    const int* ei = (const int*)d_in[1];
    const float* W = (const float*)d_in[2];
    const float* bias = (const float*)d_in[3];
    float* out = (float*)d_out;

    const size_t wbt_bytes = align256((size_t)NA * 2 * DIM * DIM * 2);   // 256 KB
    const size_t bondb_bytes = align256((size_t)NN * DIM * 2);           // 25.6 MB
    const size_t y_bytes = align256((size_t)NA * 2 * NN * DIM * 2);      // 204.8 MB
    const size_t counts_bytes = align256((size_t)NBINS * 4);             // 1.6 MB
    const size_t offsets_bytes = align256(((size_t)NBINS + 1) * 4);      // 1.6 MB
    const size_t woff_bytes = align256((size_t)NBINS * 4);               // 1.6 MB
    const size_t bsum_bytes = align256((size_t)512 * 4);                 // 2 KB
    const size_t ssrc_bytes = align256((size_t)NA * NE * 4);             // 8 MB

    const size_t base_bytes = wbt_bytes + bondb_bytes + y_bytes;
    const size_t full_bytes = base_bytes + counts_bytes + offsets_bytes +
                              woff_bytes + bsum_bytes + ssrc_bytes;

    if (ws_size >= full_bytes) {
        char* p = (char*)d_ws;
        u16* WbT = (u16*)p;                 p += wbt_bytes;
        u16* bondB = (u16*)p;               p += bondb_bytes;
        u16* Y = (u16*)p;                   p += y_bytes;
        int* counts = (int*)p;              p += counts_bytes;
        int* offsets = (int*)p;             p += offsets_bytes;
        int* woff = (int*)p;                p += woff_bytes;
        int* bsum = (int*)p;                p += bsum_bytes;
        int* ssrc = (int*)p;

        // projections
        pack_w<<<dim3(131072 / 256), 256, 0, stream>>>(W, WbT);
        cast_bond<<<dim3((NN * DIM / 8 + 255) / 256), 256, 0, stream>>>(bond, bondB);
        gemm_y<<<dim3((NN + 63) / 64), 256, 0, stream>>>(bondB, WbT, bias, Y);

        // CSR build
        hipMemsetAsync(counts, 0, (size_t)NBINS * 4, stream);
        hist_kernel<<<dim3((NE + 255) / 256, NA), 256, 0, stream>>>(ei, counts);
        scan_reduce<<<dim3(NBLK), 256, 0, stream>>>(counts, bsum);
        scan_bases<<<dim3(1), 512, 0, stream>>>(bsum, offsets);
        scan_write<<<dim3(NBLK), 256, 0, stream>>>(counts, bsum, offsets, woff);
        scatter_kernel<<<dim3((NE + 255) / 256, NA), 256, 0, stream>>>(ei, woff, ssrc);

        // gather phase: one wave per (node, head); writes every output once
        gather_kernel<<<dim3(NN / 4, NA), 256, 0, stream>>>(offsets, ssrc, Y, bondB, out);
    } else if (ws_size >= base_bytes) {
        u16* WbT = (u16*)d_ws;
        u16* bondB = (u16*)((char*)d_ws + wbt_bytes);
        u16* Y = (u16*)((char*)d_ws + wbt_bytes + bondb_bytes);
        hipMemsetAsync(d_out, 0, (size_t)out_size * sizeof(float), stream);
        pack_w<<<dim3(131072 / 256), 256, 0, stream>>>(W, WbT);
        cast_bond<<<dim3((NN * DIM / 8 + 255) / 256), 256, 0, stream>>>(bond, bondB);
        gemm_y<<<dim3((NN + 63) / 64), 256, 0, stream>>>(bondB, WbT, bias, Y);
        edge_kernel<<<dim3(NE / 4, NA), 256, 0, stream>>>(ei, Y, bond, out);
    } else {
        hipMemsetAsync(d_out, 0, (size_t)out_size * sizeof(float), stream);
        fallback_edge<<<dim3(NE, NA), 128, 0, stream>>>(bond, ei, W, bias, out);
    }
}

// Round 4
// 748.354 us; speedup vs baseline: 1.2215x; 1.0202x over previous
//
#include <hip/hip_runtime.h>
#include <hip/hip_bf16.h>
#include <stdint.h>

#define NN 100000   // nodes
#define NE 500000   // edges per head
#define NA 4        // angle heads
#define DIM 128     // bond/hidden dim
#define LDA 136     // padded LDS row stride (bf16 elems)

#define NBINS (NA * NN)          // 400000 (k-major bins)
#define SCAN_CHUNK 1024          // elems per scan block (256 thr x 4)
#define NBLK ((NBINS + SCAN_CHUNK - 1) / SCAN_CHUNK)  // 391
#define NEDGE_TOT (NA * NE)      // 2000000

typedef __attribute__((ext_vector_type(8))) short bf16x8;
typedef __attribute__((ext_vector_type(4))) float f32x4;
typedef unsigned short u16;
typedef unsigned int u32;
typedef unsigned long long u64;

__device__ __forceinline__ u16 f2bf(float x) {
    u32 u = __float_as_uint(x);
    u32 r = (u + 0x7fffu + ((u >> 16) & 1u)) >> 16;  // RNE
    return (u16)r;
}
__device__ __forceinline__ float bf2f(u16 h) {
    return __uint_as_float(((u32)h) << 16);
}
__device__ __forceinline__ float fast_tanh(float x) {
    float t = __expf(2.0f * x);
    return 1.0f - __fdividef(2.0f, t + 1.0f);
}

// ---- fused: cast bond fp32->bf16 (blocks 0..6249) + pack W (blocks 6250..6761) ----
#define CAST_BLKS 6250   // NN*DIM/8/256
#define PACK_BLKS 512    // 131072/256
__global__ __launch_bounds__(256) void cast_pack(const float* __restrict__ x,
                                                 u16* __restrict__ y,
                                                 const float* __restrict__ W,
                                                 u16* __restrict__ WbT) {
    if (blockIdx.x < CAST_BLKS) {
        int i = blockIdx.x * 256 + threadIdx.x;
        const float4* xv = (const float4*)x;
        float4 a = xv[2 * i], b = xv[2 * i + 1];
        uint4 o;
        o.x = (u32)f2bf(a.x) | ((u32)f2bf(a.y) << 16);
        o.y = (u32)f2bf(a.z) | ((u32)f2bf(a.w) << 16);
        o.z = (u32)f2bf(b.x) | ((u32)f2bf(b.y) << 16);
        o.w = (u32)f2bf(b.z) | ((u32)f2bf(b.w) << 16);
        ((uint4*)y)[i] = o;
    } else {
        int i = (blockIdx.x - CAST_BLKS) * 256 + threadIdx.x;  // 131072 total
        int d = i & 127;
        int o = (i >> 7) & 127;
        int st = i >> 14;  // slab
        WbT[i] = f2bf(W[(size_t)(st * 128 + d) * 128 + o]);
    }
}

// ---- Y[slab][node][128] bf16 = bond @ Wslab (+bias on t==0 slabs) ----
__global__ __launch_bounds__(256) void gemm_y(const u16* __restrict__ bondB,
                                              const u16* __restrict__ WbT,
                                              const float* __restrict__ bias,
                                              u16* __restrict__ Y) {
    __shared__ __align__(16) u16 As[64 * LDA];
    __shared__ __align__(16) u16 Bs[128 * LDA];
    const int node0 = blockIdx.x * 64;
    const int tid = threadIdx.x;

#pragma unroll
    for (int it = 0; it < 4; ++it) {
        int idx = it * 256 + tid;
        int row = idx >> 4, ch = idx & 15;
        int gr = node0 + row;
        if (gr >= NN) gr = NN - 1;
        *(uint4*)&As[row * LDA + ch * 8] = *(const uint4*)&bondB[(size_t)gr * DIM + ch * 8];
    }

    const int wave = tid >> 6, lane = tid & 63;
    const int m0 = wave * 16;
    const int lrow = lane & 15;
    const int lk8 = (lane >> 4) * 8;
    const int rbase = (lane >> 4) * 4;

    for (int slab = 0; slab < 8; ++slab) {
        __syncthreads();  // all waves done reading Bs (or done staging As)
        const u16* Wslab = WbT + (size_t)slab * DIM * DIM;
#pragma unroll
        for (int it = 0; it < 8; ++it) {
            int idx = it * 256 + tid;
            *(uint4*)&Bs[(idx >> 4) * LDA + (idx & 15) * 8] = *(const uint4*)&Wslab[idx * 8];
        }
        __syncthreads();

        f32x4 acc[8] = {};
#pragma unroll
        for (int kk = 0; kk < 4; ++kk) {
            int ko = kk * 32 + lk8;
            bf16x8 a = *(const bf16x8*)&As[(m0 + lrow) * LDA + ko];
#pragma unroll
            for (int nb = 0; nb < 8; ++nb) {
                bf16x8 b = *(const bf16x8*)&Bs[(nb * 16 + lrow) * LDA + ko];
                acc[nb] = __builtin_amdgcn_mfma_f32_16x16x32_bf16(a, b, acc[nb], 0, 0, 0);
            }
        }

        const int k = slab >> 1, t = slab & 1;
#pragma unroll
        for (int nb = 0; nb < 8; ++nb) {
            int o = nb * 16 + lrow;
            float bv = (t == 0) ? bias[k * DIM + o] : 0.0f;
#pragma unroll
            for (int r = 0; r < 4; ++r) {
                int node = node0 + m0 + rbase + r;
                if (node < NN)
                    Y[(size_t)slab * NN * DIM + (size_t)node * DIM + o] = f2bf(acc[nb][r] + bv);
            }
        }
    }
}

// ==================== CSR build (counting sort by dst) ====================

__global__ __launch_bounds__(256) void hist_kernel(const int* __restrict__ ei,
                                                   int* __restrict__ counts) {
    int k = blockIdx.y;
    int e = blockIdx.x * 256 + threadIdx.x;
    if (e >= NE) return;
    int dst = ei[(size_t)(k * 2 + 1) * NE + e];
    atomicAdd(&counts[k * NN + dst], 1);
}

__global__ __launch_bounds__(256) void scan_reduce(const int* __restrict__ counts,
                                                   int* __restrict__ blockSums) {
    int b = blockIdx.x, t = threadIdx.x;
    int base = b * SCAN_CHUNK + t * 4;
    int s = 0;
#pragma unroll
    for (int u = 0; u < 4; ++u) {
        int i = base + u;
        if (i < NBINS) s += counts[i];
    }
    __shared__ int red[256];
    red[t] = s;
    __syncthreads();
    for (int off = 128; off > 0; off >>= 1) {
        if (t < off) red[t] += red[t + off];
        __syncthreads();
    }
    if (t == 0) blockSums[b] = red[0];
}

// v2: parallel Hillis-Steele scan (was 1-thread serial over 391 -> ~whole-GPU idle)
__global__ void scan_bases(int* __restrict__ blockSums, int* __restrict__ offsets) {
    __shared__ int lds[512];
    int t = threadIdx.x;
    lds[t] = (t < NBLK) ? blockSums[t] : 0;
    __syncthreads();
    for (int off = 1; off < 512; off <<= 1) {
        int v = (t >= off) ? lds[t - off] : 0;
        __syncthreads();
        lds[t] += v;
        __syncthreads();
    }
    // lds now inclusive scan; entries >= NBLK padded with 0 contribute nothing
    if (t < NBLK) blockSums[t] = (t == 0) ? 0 : lds[t - 1];
    if (t == 0) offsets[NBINS] = lds[NBLK - 1];  // total = NA*NE
}

__global__ __launch_bounds__(256) void scan_write(const int* __restrict__ counts,
                                                  const int* __restrict__ blockBases,
                                                  int* __restrict__ offsets,
                                                  int* __restrict__ woff) {
    int b = blockIdx.x, t = threadIdx.x;
    int base = b * SCAN_CHUNK + t * 4;
    int v[4];
    int s = 0;
#pragma unroll
    for (int u = 0; u < 4; ++u) {
        int i = base + u;
        v[u] = (i < NBINS) ? counts[i] : 0;
        s += v[u];
    }
    __shared__ int lds[256];
    lds[t] = s;
    __syncthreads();
    for (int off = 1; off < 256; off <<= 1) {
        int add = (t >= off) ? lds[t - off] : 0;
        __syncthreads();
        lds[t] += add;
        __syncthreads();
    }
    int run = blockBases[b] + lds[t] - s;  // exclusive within block + block base
#pragma unroll
    for (int u = 0; u < 4; ++u) {
        int i = base + u;
        if (i < NBINS) {
            offsets[i] = run;
            woff[i] = run;
            run += v[u];
        }
    }
}

__global__ __launch_bounds__(256) void scatter_kernel(const int* __restrict__ ei,
                                                      int* __restrict__ woff,
                                                      int* __restrict__ sorted_src) {
    int k = blockIdx.y;
    int e = blockIdx.x * 256 + threadIdx.x;
    if (e >= NE) return;
    int src = ei[(size_t)(k * 2 + 0) * NE + e];
    int dst = ei[(size_t)(k * 2 + 1) * NE + e];
    int pos = atomicAdd(&woff[k * NN + dst], 1);
    sorted_src[pos] = src;
}

// ---- gather edge phase ----
// v5: FOUR bins (consecutive nodes, same head) per wave. Consecutive bins'
//     edges are contiguous in sorted_src, so one 16B offsets load + shared
//     64-wide src chunks + 4 prefetched y1 rows amortize the 3-deep
//     dependent-load prologue 4x. EDGE math = proven r3 form.
__global__ __launch_bounds__(256) void gather_kernel(const int* __restrict__ offsets,
                                                     const int* __restrict__ sorted_src,
                                                     const u16* __restrict__ Y,
                                                     const u16* __restrict__ bondB,
                                                     float* __restrict__ out) {
    const int k = blockIdx.y;
    const int wid = threadIdx.x >> 6;
    const int node0 = blockIdx.x * 16 + wid * 4;  // 4 nodes per wave
    const int lane = threadIdx.x & 63;
    const int f = lane * 2;
    const int bin0 = k * NN + node0;  // bin0 % 4 == 0 -> 16B-aligned offsets load

    // 5 bin boundaries via one int4 + one scalar load (broadcast, then SGPR)
    const int4 ob = *(const int4*)&offsets[bin0];
    const int o0 = __builtin_amdgcn_readfirstlane(ob.x);
    const int o1 = __builtin_amdgcn_readfirstlane(ob.y);
    const int o2 = __builtin_amdgcn_readfirstlane(ob.z);
    const int o3 = __builtin_amdgcn_readfirstlane(ob.w);
    const int o4 = __builtin_amdgcn_readfirstlane(offsets[bin0 + 4]);

    const u16* __restrict__ Y1p = Y + (size_t)(2 * k) * NN * DIM;
    const u16* __restrict__ Y2p = Y + (size_t)(2 * k + 1) * NN * DIM;

    // prefetch all 4 y1 rows upfront (independent loads, hide under chunk load)
    u32 y1v[4];
#pragma unroll
    for (int b = 0; b < 4; ++b)
        y1v[b] = *(const u32*)&Y1p[(u32)(node0 + b) * DIM + f];

    // first src chunk
    int chunkBase = o0;
    int chunkEnd = o0 + 64;
    int g0 = chunkBase + lane;
    g0 = (g0 < NEDGE_TOT) ? g0 : (NEDGE_TOT - 1);
    int srcl = sorted_src[g0];

    const int ends[4] = {o1, o2, o3, o4};
    int m = o0;

#define EDGE(w, x)                                                      \
    {                                                                   \
        float p0 = y1a + __uint_as_float((w) << 16);                    \
        float p1 = y1b + __uint_as_float((w) & 0xffff0000u);            \
        float e0 = __expf(2.0f * p0);                                   \
        float e1 = __expf(2.0f * p1);                                   \
        float d0 = e0 + 1.0f;                                           \
        float d1 = e1 + 1.0f;                                           \
        float r = __fdividef(1.0f, d0 * d1);                            \
        float th0 = fmaf(-2.0f * d1, r, 1.0f);                          \
        float th1 = fmaf(-2.0f * d0, r, 1.0f);                          \
        acc0 = fmaf(th0, __uint_as_float((x) << 16), acc0);             \
        acc1 = fmaf(th1, __uint_as_float((x) & 0xffff0000u), acc1);     \
    }

#pragma unroll
    for (int b = 0; b < 4; ++b) {
        const float y1a = __uint_as_float(y1v[b] << 16);
        const float y1b = __uint_as_float(y1v[b] & 0xffff0000u);
        const int e_end = ends[b];
        float acc0 = 0.0f, acc1 = 0.0f;

        while (m < e_end) {
            if (m >= chunkEnd) {
                chunkBase = m;
                chunkEnd = m + 64;
                int g = chunkBase + lane;
                g = (g < NEDGE_TOT) ? g : (NEDGE_TOT - 1);
                srcl = sorted_src[g];
            }
            const int lim = (e_end < chunkEnd) ? e_end : chunkEnd;
            for (; m + 4 <= lim; m += 4) {
                const int idx = m - chunkBase;
                const int s0 = __builtin_amdgcn_readlane(srcl, idx);
                const int s1 = __builtin_amdgcn_readlane(srcl, idx + 1);
                const int s2 = __builtin_amdgcn_readlane(srcl, idx + 2);
                const int s3 = __builtin_amdgcn_readlane(srcl, idx + 3);
                const u32 w0 = *(const u32*)&Y2p[(u32)s0 * DIM + f];
                const u32 x0 = *(const u32*)&bondB[(u32)s0 * DIM + f];
                const u32 w1 = *(const u32*)&Y2p[(u32)s1 * DIM + f];
                const u32 x1 = *(const u32*)&bondB[(u32)s1 * DIM + f];
                const u32 w2 = *(const u32*)&Y2p[(u32)s2 * DIM + f];
                const u32 x2 = *(const u32*)&bondB[(u32)s2 * DIM + f];
                const u32 w3 = *(const u32*)&Y2p[(u32)s3 * DIM + f];
                const u32 x3 = *(const u32*)&bondB[(u32)s3 * DIM + f];
                EDGE(w0, x0);
                EDGE(w1, x1);
                EDGE(w2, x2);
                EDGE(w3, x3);
            }
            for (; m < lim; ++m) {
                const int s = __builtin_amdgcn_readlane(srcl, m - chunkBase);
                const u32 w = *(const u32*)&Y2p[(u32)s * DIM + f];
                const u32 x = *(const u32*)&bondB[(u32)s * DIM + f];
                EDGE(w, x);
            }
        }

        u64 uv = ((u64)__float_as_uint(acc1) << 32) | (u64)__float_as_uint(acc0);
        __builtin_nontemporal_store(
            uv, (u64*)(out + (size_t)(node0 + b) * (NA * DIM) + k * DIM + f));
    }
#undef EDGE
}

// ---- legacy atomic edge kernel (mid fallback) ----
__global__ __launch_bounds__(256) void edge_kernel(const int* __restrict__ ei,
                                                   const u16* __restrict__ Y,
                                                   const float* __restrict__ bond,
                                                   float* __restrict__ out) {
    const int k = blockIdx.y;
    const int e = blockIdx.x * 4 + (threadIdx.x >> 6);
    const int lane = threadIdx.x & 63;
    const int src = ei[(size_t)(k * 2 + 0) * NE + e];
    const int dst = ei[(size_t)(k * 2 + 1) * NE + e];
    const int f = lane * 2;
    const u32 y1p = *(const u32*)&Y[((size_t)(k * 2 + 0) * NN + dst) * DIM + f];
    const u32 y2p = *(const u32*)&Y[((size_t)(k * 2 + 1) * NN + src) * DIM + f];
    const float2 xj = *(const float2*)&bond[(size_t)src * DIM + f];
    float p0 = bf2f((u16)(y1p & 0xffffu)) + bf2f((u16)(y2p & 0xffffu));
    float p1 = bf2f((u16)(y1p >> 16)) + bf2f((u16)(y2p >> 16));
    float a0 = fast_tanh(p0);
    float a1 = fast_tanh(p1);
    float* op = out + (size_t)dst * (NA * DIM) + k * DIM + f;
    atomicAdd(op, a0 * xj.x);
    atomicAdd(op + 1, a1 * xj.y);
}

// ---- ultra fallback: direct per-edge compute ----
__global__ __launch_bounds__(128) void fallback_edge(const float* __restrict__ bond,
                                                     const int* __restrict__ ei,
                                                     const float* __restrict__ W,
                                                     const float* __restrict__ bias,
                                                     float* __restrict__ out) {
    __shared__ float xi[DIM], xj[DIM];
    const int k = blockIdx.y;
    const int e = blockIdx.x;
    const int o = threadIdx.x;
    const int src = ei[(size_t)(k * 2 + 0) * NE + e];
    const int dst = ei[(size_t)(k * 2 + 1) * NE + e];
    xi[o] = bond[(size_t)dst * DIM + o];
    xj[o] = bond[(size_t)src * DIM + o];
    __syncthreads();
    const float* Wk = W + (size_t)k * 2 * DIM * DIM;
    float acc = bias[k * DIM + o];
    for (int din = 0; din < DIM; ++din) {
        acc += xi[din] * Wk[din * DIM + o];
        acc += xj[din] * Wk[(DIM + din) * DIM + o];
    }
    float alpha = fast_tanh(acc);
    atomicAdd(&out[(size_t)dst * (NA * DIM) + k * DIM + o], alpha * xj[o]);
}

static inline size_t align256(size_t x) { return (x + 255) & ~(size_t)255; }

extern "C" void kernel_launch(void* const* d_in, const int* in_sizes, int n_in,
                              void* d_out, int out_size, void* d_ws, size_t ws_size,
                              hipStream_t stream) {
    const float* bond = (const float*)d_in[0];
    const int* ei = (const int*)d_in[1];
    const float* W = (const float*)d_in[2];
    const float* bias = (const float*)d_in[3];
    float* out = (float*)d_out;

    const size_t wbt_bytes = align256((size_t)NA * 2 * DIM * DIM * 2);   // 256 KB
    const size_t bondb_bytes = align256((size_t)NN * DIM * 2);           // 25.6 MB
    const size_t y_bytes = align256((size_t)NA * 2 * NN * DIM * 2);      // 204.8 MB
    const size_t counts_bytes = align256((size_t)NBINS * 4);             // 1.6 MB
    const size_t offsets_bytes = align256(((size_t)NBINS + 8) * 4);      // 1.6 MB
    const size_t woff_bytes = align256((size_t)NBINS * 4);               // 1.6 MB
    const size_t bsum_bytes = align256((size_t)512 * 4);                 // 2 KB
    const size_t ssrc_bytes = align256((size_t)NA * NE * 4 + 256);       // 8 MB

    const size_t base_bytes = wbt_bytes + bondb_bytes + y_bytes;
    const size_t full_bytes = base_bytes + counts_bytes + offsets_bytes +
                              woff_bytes + bsum_bytes + ssrc_bytes;

    if (ws_size >= full_bytes) {
        char* p = (char*)d_ws;
        u16* WbT = (u16*)p;                 p += wbt_bytes;
        u16* bondB = (u16*)p;               p += bondb_bytes;
        u16* Y = (u16*)p;                   p += y_bytes;
        int* counts = (int*)p;              p += counts_bytes;
        int* offsets = (int*)p;             p += offsets_bytes;
        int* woff = (int*)p;                p += woff_bytes;
        int* bsum = (int*)p;                p += bsum_bytes;
        int* ssrc = (int*)p;

        // projections (cast + pack fused into one launch)
        cast_pack<<<dim3(CAST_BLKS + PACK_BLKS), 256, 0, stream>>>(bond, bondB, W, WbT);
        gemm_y<<<dim3((NN + 63) / 64), 256, 0, stream>>>(bondB, WbT, bias, Y);

        // CSR build
        hipMemsetAsync(counts, 0, (size_t)NBINS * 4, stream);
        hist_kernel<<<dim3((NE + 255) / 256, NA), 256, 0, stream>>>(ei, counts);
        scan_reduce<<<dim3(NBLK), 256, 0, stream>>>(counts, bsum);
        scan_bases<<<dim3(1), 512, 0, stream>>>(bsum, offsets);
        scan_write<<<dim3(NBLK), 256, 0, stream>>>(counts, bsum, offsets, woff);
        scatter_kernel<<<dim3((NE + 255) / 256, NA), 256, 0, stream>>>(ei, woff, ssrc);

        // gather phase: 4 bins per wave, 16 nodes per block
        gather_kernel<<<dim3(NN / 16, NA), 256, 0, stream>>>(offsets, ssrc, Y, bondB, out);
    } else if (ws_size >= base_bytes) {
        u16* WbT = (u16*)d_ws;
        u16* bondB = (u16*)((char*)d_ws + wbt_bytes);
        u16* Y = (u16*)((char*)d_ws + wbt_bytes + bondb_bytes);
        hipMemsetAsync(d_out, 0, (size_t)out_size * sizeof(float), stream);
        cast_pack<<<dim3(CAST_BLKS + PACK_BLKS), 256, 0, stream>>>(bond, bondB, W, WbT);
        gemm_y<<<dim3((NN + 63) / 64), 256, 0, stream>>>(bondB, WbT, bias, Y);
        edge_kernel<<<dim3(NE / 4, NA), 256, 0, stream>>>(ei, Y, bond, out);
    } else {
        hipMemsetAsync(d_out, 0, (size_t)out_size * sizeof(float), stream);
        fallback_edge<<<dim3(NE, NA), 128, 0, stream>>>(bond, ei, W, bias, out);
    }
}